// Round 1
// baseline (1156.231 us; speedup 1.0000x reference)
//
#include <hip/hip_runtime.h>
#include <hip/hip_bf16.h>

// AWQ w4a16 GEMM + fused LoRA, MI355X (gfx950).
// Strategy: fold dequant + LoRA into one bf16 MFMA GEMM.
//   Xe  [8192][4160] bf16 = [ x (bf16) | t = x @ lora_a (bf16) ]
//   Wt  [11008][4160] bf16 = [ ((q - z) * s)^T | lora_b^T ]
//   out [8192][11008] f32 = Xe @ Wt^T     (K' = 4160)
// GEMM is the m97-verified structure: 128x128 tile, BK=64, 4 waves (2x2),
// mfma_f32_16x16x32_bf16, global_load_lds width 16, pre-swizzled global
// source + XOR-swizzled ds_read (both-sides swizzle, rule #21).

typedef __bf16 bf16x8 __attribute__((ext_vector_type(8)));
typedef float f32x4 __attribute__((ext_vector_type(4)));

#define GLOAD_LDS16(gp, lp)                                                    \
  __builtin_amdgcn_global_load_lds(                                            \
      (const __attribute__((address_space(1))) void*)(gp),                     \
      (__attribute__((address_space(3))) void*)(lp), 16, 0, 0)

__device__ __forceinline__ unsigned short f2b(float f) {
  unsigned int u = __builtin_bit_cast(unsigned int, f);
  unsigned int r = u + 0x7fffu + ((u >> 16) & 1u);  // RTNE
  return (unsigned short)(r >> 16);
}

constexpr int M_DIM = 8192;
constexpr int K_DIM = 4096;
constexpr int N_DIM = 11008;
constexpr int R_DIM = 64;
constexpr int KP = K_DIM + R_DIM;  // 4160, K' with LoRA folded in

// ---------------------------------------------------------------- prep: x -> bf16
__global__ __launch_bounds__(256) void cvt_x_kernel(
    const float* __restrict__ x, unsigned short* __restrict__ Xe) {
  const size_t total8 = (size_t)M_DIM * (K_DIM / 8);  // 8-elem chunks
  for (size_t idx = (size_t)blockIdx.x * 256 + threadIdx.x; idx < total8;
       idx += (size_t)gridDim.x * 256) {
    const size_t m = idx >> 9;          // K/8 = 512 chunks per row
    const size_t k8 = idx & 511;
    const float4* p = (const float4*)(x + (m << 12) + (k8 << 3));
    const float4 v0 = p[0], v1 = p[1];
    unsigned short h[8] = {f2b(v0.x), f2b(v0.y), f2b(v0.z), f2b(v0.w),
                           f2b(v1.x), f2b(v1.y), f2b(v1.z), f2b(v1.w)};
    *(uint4*)(Xe + m * KP + (k8 << 3)) = *(const uint4*)h;
  }
}

// ---------------------------------------------------------------- prep: t = x @ lora_a
// Block: 256 thr handles 16 rows x 64 cols of t; K chunks of 128 staged in LDS.
__global__ __launch_bounds__(256) void lora_t_kernel(
    const float* __restrict__ x, const float* __restrict__ A,
    unsigned short* __restrict__ Xe) {
  __shared__ float xs[16][128];
  __shared__ float as[128][64];
  const int tid = threadIdx.x;
  const int r0 = blockIdx.x * 16;
  const int c = tid & 63;
  const int rg = tid >> 6;  // == wave id -> xs reads are wave-uniform broadcasts
  float acc[4] = {0.f, 0.f, 0.f, 0.f};
  for (int kc = 0; kc < K_DIM; kc += 128) {
    __syncthreads();
#pragma unroll
    for (int i = 0; i < 2; ++i) {
      const int flat = i * 1024 + tid * 4;
      const int row = flat >> 7, col = flat & 127;
      *(float4*)&xs[row][col] =
          *(const float4*)(x + (size_t)(r0 + row) * K_DIM + kc + col);
    }
#pragma unroll
    for (int j = 0; j < 8; ++j)
      ((float4*)as)[j * 256 + tid] =
          ((const float4*)(A + (size_t)kc * R_DIM))[j * 256 + tid];
    __syncthreads();
#pragma unroll 8
    for (int kk = 0; kk < 128; ++kk) {
      const float b = as[kk][c];
#pragma unroll
      for (int i = 0; i < 4; ++i) acc[i] += xs[rg * 4 + i][kk] * b;
    }
  }
#pragma unroll
  for (int i = 0; i < 4; ++i)
    Xe[(size_t)(r0 + rg * 4 + i) * KP + K_DIM + c] = f2b(acc[i]);
}

// ---------------------------------------------------------------- prep: dequant + transpose
// Tile 64k x 64n; read qweight coalesced, LDS transpose, write Wt[n][k] coalesced.
__global__ __launch_bounds__(256) void dequant_kernel(
    const int* __restrict__ qw, const int* __restrict__ qz,
    const float* __restrict__ sc, unsigned short* __restrict__ Wt) {
  __shared__ unsigned short w_lds[64][68];  // +4 pad -> ~2-way banks
  const int tid = threadIdx.x;
  const int n0 = blockIdx.x * 64, k0 = blockIdx.y * 64;
  const int g = k0 >> 7;  // group = k/128 (64-tile never crosses a group)
  const int nl = tid & 63;
  const int kl0 = tid >> 6;
  const int zv = qz[(size_t)g * N_DIM + n0 + nl];
  const float sv = sc[(size_t)g * N_DIM + n0 + nl];
#pragma unroll
  for (int i = 0; i < 16; ++i) {
    const int kl = i * 4 + kl0;
    const int q = qw[(size_t)(k0 + kl) * N_DIM + n0 + nl];
    w_lds[nl][kl] = f2b((float)(q - zv) * sv);
  }
  __syncthreads();
#pragma unroll
  for (int p = 0; p < 2; ++p) {
    const int chunk = p * 256 + tid;
    const int nr = chunk >> 3, k8 = chunk & 7;
    const unsigned short* rp = &w_lds[nr][k8 * 8];
    const uint2 lo = *(const uint2*)rp;
    const uint2 hi = *(const uint2*)(rp + 4);
    uint4 v;
    v.x = lo.x; v.y = lo.y; v.z = hi.x; v.w = hi.y;
    *(uint4*)(Wt + (size_t)(n0 + nr) * KP + k0 + k8 * 8) = v;
  }
}

// ---------------------------------------------------------------- prep: lora_b^T into Wt cols [4096,4160)
__global__ __launch_bounds__(256) void lorab_t_kernel(
    const float* __restrict__ B, unsigned short* __restrict__ Wt) {
  __shared__ unsigned short b_lds[64][68];
  const int tid = threadIdx.x;
  const int n0 = blockIdx.x * 64;
  const int nl = tid & 63;
  const int rl0 = tid >> 6;
#pragma unroll
  for (int i = 0; i < 16; ++i) {
    const int rl = i * 4 + rl0;
    b_lds[nl][rl] = f2b(B[(size_t)rl * N_DIM + n0 + nl]);
  }
  __syncthreads();
#pragma unroll
  for (int p = 0; p < 2; ++p) {
    const int chunk = p * 256 + tid;
    const int nr = chunk >> 3, r8 = chunk & 7;
    const unsigned short* rp = &b_lds[nr][r8 * 8];
    const uint2 lo = *(const uint2*)rp;
    const uint2 hi = *(const uint2*)(rp + 4);
    uint4 v;
    v.x = lo.x; v.y = lo.y; v.z = hi.x; v.w = hi.y;
    *(uint4*)(Wt + (size_t)(n0 + nr) * KP + K_DIM + r8 * 8) = v;
  }
}

// ---------------------------------------------------------------- main GEMM
// 128x128 tile, BK=64, 256 thr = 4 waves (2x2), each wave 64x64 out (4x4 frags).
// LDS tiles [128][64] bf16, linear dest for global_load_lds; the global SOURCE
// per lane is chunk-permuted (c ^= row&7) so swizzled ds_reads are conflict-free.
__global__ __launch_bounds__(256) void gemm_kernel(
    const unsigned short* __restrict__ Xe, const unsigned short* __restrict__ Wt,
    float* __restrict__ out) {
  __shared__ unsigned short As[128 * 64];
  __shared__ unsigned short Bs[128 * 64];
  const int tid = threadIdx.x;
  const int wave = tid >> 6, lane = tid & 63;
  const int bn = blockIdx.x, bm = blockIdx.y;
  const int wr = wave >> 1, wc = wave & 1;

  // staging: call i covers rows [i*32, i*32+32); wave w rows [i*32+w*8, +8)
  // lane l -> row offset l>>3, physical chunk l&7 holds logical chunk (l&7)^(l>>3)
  const int srow = wave * 8 + (lane >> 3);
  const int schunk = (lane & 7) ^ (lane >> 3);
  const unsigned short* gA = Xe + (size_t)(bm * 128 + srow) * KP + schunk * 8;
  const unsigned short* gB = Wt + (size_t)(bn * 128 + srow) * KP + schunk * 8;

  f32x4 acc[4][4];
#pragma unroll
  for (int m = 0; m < 4; ++m)
#pragma unroll
    for (int n = 0; n < 4; ++n) acc[m][n] = (f32x4){0.f, 0.f, 0.f, 0.f};

  // fragment read offsets (bytes). row&7 == lane&7 for all frag rows.
  const int rA = (wr * 64 + (lane & 15)) * 128;
  const int rB = (wc * 64 + (lane & 15)) * 128;
  const int coff0 = (((lane >> 4)) ^ (lane & 7)) << 4;
  const int coff1 = ((4 + (lane >> 4)) ^ (lane & 7)) << 4;

  for (int kt = 0; kt < KP / 64; ++kt) {
#pragma unroll
    for (int i = 0; i < 4; ++i) {
      GLOAD_LDS16(gA + (size_t)i * 32 * KP + kt * 64, As + (i * 32 + wave * 8) * 64);
      GLOAD_LDS16(gB + (size_t)i * 32 * KP + kt * 64, Bs + (i * 32 + wave * 8) * 64);
    }
    __syncthreads();
#pragma unroll
    for (int kk = 0; kk < 2; ++kk) {
      const int coff = kk ? coff1 : coff0;
      bf16x8 a[4], b[4];
#pragma unroll
      for (int m = 0; m < 4; ++m)
        a[m] = *(const bf16x8*)((const char*)As + rA + m * 2048 + coff);
#pragma unroll
      for (int n = 0; n < 4; ++n)
        b[n] = *(const bf16x8*)((const char*)Bs + rB + n * 2048 + coff);
#pragma unroll
      for (int m = 0; m < 4; ++m)
#pragma unroll
        for (int n = 0; n < 4; ++n)
          acc[m][n] =
              __builtin_amdgcn_mfma_f32_16x16x32_bf16(a[m], b[n], acc[m][n], 0, 0, 0);
    }
    __syncthreads();
  }

  // epilogue: C/D layout col=lane&15, row=(lane>>4)*4+j
  const int orow = bm * 128 + wr * 64 + ((lane >> 4) << 2);
  const int ocol = bn * 128 + wc * 64 + (lane & 15);
#pragma unroll
  for (int m = 0; m < 4; ++m)
#pragma unroll
    for (int n = 0; n < 4; ++n)
#pragma unroll
      for (int j = 0; j < 4; ++j)
        out[(size_t)(orow + m * 16 + j) * N_DIM + ocol + n * 16] = acc[m][n][j];
}

// ---------------------------------------------------------------- launch
extern "C" void kernel_launch(void* const* d_in, const int* in_sizes, int n_in,
                              void* d_out, int out_size, void* d_ws, size_t ws_size,
                              hipStream_t stream) {
  const float* x = (const float*)d_in[0];
  const float* scales = (const float*)d_in[1];
  const float* lora_a = (const float*)d_in[2];
  const float* lora_b = (const float*)d_in[3];
  const int* qweight = (const int*)d_in[4];
  const int* qzeros = (const int*)d_in[5];
  float* out = (float*)d_out;

  // ws layout: Xe [8192][4160] bf16 (68.2 MB), Wt [11008][4160] bf16 (91.6 MB)
  unsigned short* Xe = (unsigned short*)d_ws;
  unsigned short* Wt = Xe + (size_t)M_DIM * KP;

  cvt_x_kernel<<<2048, 256, 0, stream>>>(x, Xe);
  lora_t_kernel<<<M_DIM / 16, 256, 0, stream>>>(x, lora_a, Xe);
  dequant_kernel<<<dim3(N_DIM / 64, K_DIM / 64), 256, 0, stream>>>(qweight, qzeros,
                                                                   scales, Wt);
  lorab_t_kernel<<<N_DIM / 64, 256, 0, stream>>>(lora_b, Wt);
  gemm_kernel<<<dim3(N_DIM / 128, M_DIM / 128), 256, 0, stream>>>(Xe, Wt, out);
}

// Round 2
// 910.916 us; speedup vs baseline: 1.2693x; 1.2693x over previous
//
#include <hip/hip_runtime.h>
#include <hip/hip_bf16.h>

// AWQ w4a16 GEMM + fused LoRA, MI355X (gfx950).
//   Xe  [8192][4160] bf16 = [ x (bf16) | t = x @ lora_a (bf16) ]
//   Wt  [11008][4160] bf16 = [ ((q - z) * s)^T | lora_b^T ]
//   out [8192][11008] f32 = Xe @ Wt^T     (K' = 4160, NT = 65 K-tiles of 64)
// GEMM: 256x256 8-phase template (T1 XCD swizzle, T2 chunk-XOR swizzle via
// pre-swizzled global source, T3+T4 counted vmcnt(4) once per K-tile,
// T5 setprio around MFMA clusters). 512 thr = 8 waves (2M x 4N), 128 KiB LDS.

typedef __bf16 bf16x8 __attribute__((ext_vector_type(8)));
typedef float f32x4 __attribute__((ext_vector_type(4)));

#define GLOAD_LDS16(gp, lp)                                                    \
  __builtin_amdgcn_global_load_lds(                                            \
      (const __attribute__((address_space(1))) void*)(gp),                     \
      (__attribute__((address_space(3))) void*)(lp), 16, 0, 0)

#define SB0() __builtin_amdgcn_sched_barrier(0)
#define BAR() __builtin_amdgcn_s_barrier()

__device__ __forceinline__ unsigned short f2b(float f) {
  unsigned int u = __builtin_bit_cast(unsigned int, f);
  unsigned int r = u + 0x7fffu + ((u >> 16) & 1u);  // RTNE
  return (unsigned short)(r >> 16);
}

constexpr int M_DIM = 8192;
constexpr int K_DIM = 4096;
constexpr int N_DIM = 11008;
constexpr int R_DIM = 64;
constexpr int KP = K_DIM + R_DIM;  // 4160
constexpr int NT = KP / 64;        // 65 K-tiles

// ---------------------------------------------------------------- prep: x -> bf16
__global__ __launch_bounds__(256) void cvt_x_kernel(
    const float* __restrict__ x, unsigned short* __restrict__ Xe) {
  const size_t total8 = (size_t)M_DIM * (K_DIM / 8);
  for (size_t idx = (size_t)blockIdx.x * 256 + threadIdx.x; idx < total8;
       idx += (size_t)gridDim.x * 256) {
    const size_t m = idx >> 9;
    const size_t k8 = idx & 511;
    const float4* p = (const float4*)(x + (m << 12) + (k8 << 3));
    const float4 v0 = p[0], v1 = p[1];
    unsigned short h[8] = {f2b(v0.x), f2b(v0.y), f2b(v0.z), f2b(v0.w),
                           f2b(v1.x), f2b(v1.y), f2b(v1.z), f2b(v1.w)};
    *(uint4*)(Xe + m * KP + (k8 << 3)) = *(const uint4*)h;
  }
}

// ---------------------------------------------------------------- prep: t = x @ lora_a
__global__ __launch_bounds__(256) void lora_t_kernel(
    const float* __restrict__ x, const float* __restrict__ A,
    unsigned short* __restrict__ Xe) {
  __shared__ float xs[16][128];
  __shared__ float as[128][64];
  const int tid = threadIdx.x;
  const int r0 = blockIdx.x * 16;
  const int c = tid & 63;
  const int rg = tid >> 6;
  float acc[4] = {0.f, 0.f, 0.f, 0.f};
  for (int kc = 0; kc < K_DIM; kc += 128) {
    __syncthreads();
#pragma unroll
    for (int i = 0; i < 2; ++i) {
      const int flat = i * 1024 + tid * 4;
      const int row = flat >> 7, col = flat & 127;
      *(float4*)&xs[row][col] =
          *(const float4*)(x + (size_t)(r0 + row) * K_DIM + kc + col);
    }
#pragma unroll
    for (int j = 0; j < 8; ++j)
      ((float4*)as)[j * 256 + tid] =
          ((const float4*)(A + (size_t)kc * R_DIM))[j * 256 + tid];
    __syncthreads();
    for (int kk = 0; kk < 128; kk += 4) {
      float4 xv[4];
#pragma unroll
      for (int i = 0; i < 4; ++i) xv[i] = *(const float4*)&xs[rg * 4 + i][kk];
#pragma unroll
      for (int q = 0; q < 4; ++q) {
        const float b = as[kk + q][c];
        acc[0] += ((const float*)&xv[0])[q] * b;
        acc[1] += ((const float*)&xv[1])[q] * b;
        acc[2] += ((const float*)&xv[2])[q] * b;
        acc[3] += ((const float*)&xv[3])[q] * b;
      }
    }
  }
#pragma unroll
  for (int i = 0; i < 4; ++i)
    Xe[(size_t)(r0 + rg * 4 + i) * KP + K_DIM + c] = f2b(acc[i]);
}

// ---------------------------------------------------------------- prep: dequant + transpose
__global__ __launch_bounds__(256) void dequant_kernel(
    const int* __restrict__ qw, const int* __restrict__ qz,
    const float* __restrict__ sc, unsigned short* __restrict__ Wt) {
  __shared__ unsigned short w_lds[64][68];
  const int tid = threadIdx.x;
  const int n0 = blockIdx.x * 64, k0 = blockIdx.y * 64;
  const int g = k0 >> 7;
  const int nl = tid & 63;
  const int kl0 = tid >> 6;
  const int zv = qz[(size_t)g * N_DIM + n0 + nl];
  const float sv = sc[(size_t)g * N_DIM + n0 + nl];
#pragma unroll
  for (int i = 0; i < 16; ++i) {
    const int kl = i * 4 + kl0;
    const int q = qw[(size_t)(k0 + kl) * N_DIM + n0 + nl];
    w_lds[nl][kl] = f2b((float)(q - zv) * sv);
  }
  __syncthreads();
#pragma unroll
  for (int p = 0; p < 2; ++p) {
    const int chunk = p * 256 + tid;
    const int nr = chunk >> 3, k8 = chunk & 7;
    const unsigned short* rp = &w_lds[nr][k8 * 8];
    const uint2 lo = *(const uint2*)rp;
    const uint2 hi = *(const uint2*)(rp + 4);
    uint4 v;
    v.x = lo.x; v.y = lo.y; v.z = hi.x; v.w = hi.y;
    *(uint4*)(Wt + (size_t)(n0 + nr) * KP + k0 + k8 * 8) = v;
  }
}

// ---------------------------------------------------------------- prep: lora_b^T
__global__ __launch_bounds__(256) void lorab_t_kernel(
    const float* __restrict__ B, unsigned short* __restrict__ Wt) {
  __shared__ unsigned short b_lds[64][68];
  const int tid = threadIdx.x;
  const int n0 = blockIdx.x * 64;
  const int nl = tid & 63;
  const int rl0 = tid >> 6;
#pragma unroll
  for (int i = 0; i < 16; ++i) {
    const int rl = i * 4 + rl0;
    b_lds[nl][rl] = f2b(B[(size_t)rl * N_DIM + n0 + nl]);
  }
  __syncthreads();
#pragma unroll
  for (int p = 0; p < 2; ++p) {
    const int chunk = p * 256 + tid;
    const int nr = chunk >> 3, r8 = chunk & 7;
    const unsigned short* rp = &b_lds[nr][r8 * 8];
    const uint2 lo = *(const uint2*)rp;
    const uint2 hi = *(const uint2*)(rp + 4);
    uint4 v;
    v.x = lo.x; v.y = lo.y; v.z = hi.x; v.w = hi.y;
    *(uint4*)(Wt + (size_t)(n0 + nr) * KP + K_DIM + r8 * 8) = v;
  }
}

// ---------------------------------------------------------------- main GEMM (256^2, 8-phase)
// Waves: wr = w>>2 (M-half, 128 rows), wc = w&3 (N-quarter, 64 cols).
// LDS: [dbuf][op A/B][half][128*64] bf16 = 8 x 16 KiB regions, 128 KiB total.
// Per K-tile t (buf b=t&1), 4 phases:
//   P1: read A(mh0) 8 + B(nh0) 4; stage A-half0(t+1)->b^1 | MFMA Q(0,0)
//   P2: read B(nh1) 4;            stage A-half1(t+1)->b^1 | MFMA Q(0,1)
//   P3: read A(mh1) 8;            stage B-half0(t+2)->b   | MFMA Q(1,1)  [B(t) dead after P2]
//   P4: -;                        stage B-half1(t+2)->b   | MFMA Q(1,0); vmcnt(4)
// vmcnt(4) leaves P3/P4 stages (B(t+2)) in flight; forces A(t+1) landed.
__global__ __launch_bounds__(512, 2) void gemm_kernel(
    const unsigned short* __restrict__ Xe, const unsigned short* __restrict__ Wt,
    float* __restrict__ out) {
  __shared__ unsigned short lds[2][2][2][128 * 64];
  const int tid = threadIdx.x;
  const int w = tid >> 6, lane = tid & 63;
  // T1: bijective XCD swizzle, 1376 = 8 * 172
  const int orig = blockIdx.x;
  const int wg = (orig & 7) * 172 + (orig >> 3);
  const int bm = wg & 31;   // 32 M-tiles (fast-varying within an XCD slab)
  const int bn = wg >> 5;   // 43 N-tiles
  const int wr = w >> 2, wc = w & 3;

  // staging addresses: row rb, pre-swizzled logical chunk (T2 source permutation)
  const int rb = w * 8 + (lane >> 3);
  const int sc = ((lane & 7) ^ (lane >> 3)) * 8;
  const unsigned short* gA = Xe + (size_t)(bm * 256 + rb) * KP + sc;
  const unsigned short* gB = Wt + (size_t)(bn * 256 + rb) * KP + sc;

  // fragment read offsets (ushort units); row stride 64, chunk XOR on read side
  const int rowA = (lane & 15) * 64;
  const int rowB = ((wc & 1) * 64 + (lane & 15)) * 64;
  const int cx0 = (((lane >> 4) ^ (lane & 7))) * 8;
  const int cx1 = ((((lane >> 4) + 4) ^ (lane & 7))) * 8;

  f32x4 acc[8][4];
#pragma unroll
  for (int i = 0; i < 8; ++i)
#pragma unroll
    for (int j = 0; j < 4; ++j) acc[i][j] = (f32x4){0.f, 0.f, 0.f, 0.f};

  bf16x8 a[4][2], b0[2][2], b1[2][2];

  auto stage = [&](const unsigned short* g, int buf, int op, int half, int kt) {
    const unsigned short* s = g + (size_t)(half * 128) * KP + kt * 64;
    unsigned short* d = &lds[buf][op][half][w * 512];  // wave-uniform; HW adds lane*16B
    GLOAD_LDS16(s, d);
    GLOAD_LDS16(s + (size_t)64 * KP, d + 4096);
  };

#define LDA(buf, mh)                                                           \
  do {                                                                         \
    const unsigned short* R = &lds[buf][0][wr][0];                             \
    _Pragma("unroll") for (int i = 0; i < 4; ++i) {                            \
      a[i][0] = *(const bf16x8*)(R + ((mh)*4 + i) * 1024 + rowA + cx0);        \
      a[i][1] = *(const bf16x8*)(R + ((mh)*4 + i) * 1024 + rowA + cx1);        \
    }                                                                          \
  } while (0)

#define LDB(buf, dst, nh)                                                      \
  do {                                                                         \
    const unsigned short* R = &lds[buf][1][wc >> 1][0];                        \
    _Pragma("unroll") for (int j = 0; j < 2; ++j) {                            \
      dst[j][0] = *(const bf16x8*)(R + ((nh)*2 + j) * 1024 + rowB + cx0);      \
      dst[j][1] = *(const bf16x8*)(R + ((nh)*2 + j) * 1024 + rowB + cx1);      \
    }                                                                          \
  } while (0)

#define MFMAQ(mh, bb, nh)                                                      \
  do {                                                                         \
    _Pragma("unroll") for (int ks = 0; ks < 2; ++ks)                           \
    _Pragma("unroll") for (int i = 0; i < 4; ++i)                              \
    _Pragma("unroll") for (int j = 0; j < 2; ++j)                              \
      acc[(mh)*4 + i][(nh)*2 + j] = __builtin_amdgcn_mfma_f32_16x16x32_bf16(   \
          a[i][ks], bb[j][ks], acc[(mh)*4 + i][(nh)*2 + j], 0, 0, 0);          \
  } while (0)

#define PHASE_SYNC_IN()  do { SB0(); BAR(); SB0(); } while (0)
#define PRIO_ON()  do { __builtin_amdgcn_s_setprio(1); SB0(); } while (0)
#define PRIO_OFF() do { SB0(); __builtin_amdgcn_s_setprio(0); } while (0)

  // prologue: tile0 A+B, tile1 B. (tile1 A staged during tile0 P1/P2.)
  stage(gA, 0, 0, 0, 0); stage(gA, 0, 0, 1, 0);
  stage(gB, 0, 1, 0, 0); stage(gB, 0, 1, 1, 0);
  stage(gB, 1, 1, 0, 1); stage(gB, 1, 1, 1, 1);
  asm volatile("s_waitcnt vmcnt(4)" ::: "memory");  // tile0 landed; tile1 B in flight
  PHASE_SYNC_IN();

  for (int kt = 0; kt < NT; ++kt) {
    const int buf = kt & 1;
    const bool s1 = kt + 1 < NT, s2 = kt + 2 < NT;
    // ---- P1
    LDA(buf, 0);
    LDB(buf, b0, 0);
    if (s1) stage(gA, buf ^ 1, 0, 0, kt + 1);
    PHASE_SYNC_IN();
    PRIO_ON();  MFMAQ(0, b0, 0);  PRIO_OFF();
    PHASE_SYNC_IN();
    // ---- P2
    LDB(buf, b1, 1);
    if (s1) stage(gA, buf ^ 1, 0, 1, kt + 1);
    PHASE_SYNC_IN();
    PRIO_ON();  MFMAQ(0, b1, 1);  PRIO_OFF();
    PHASE_SYNC_IN();
    // ---- P3
    LDA(buf, 1);
    if (s2) stage(gB, buf, 1, 0, kt + 2);
    PHASE_SYNC_IN();
    PRIO_ON();  MFMAQ(1, b1, 1);  PRIO_OFF();
    PHASE_SYNC_IN();
    // ---- P4
    if (s2) stage(gB, buf, 1, 1, kt + 2);
    PHASE_SYNC_IN();
    PRIO_ON();  MFMAQ(1, b0, 0);  PRIO_OFF();
    SB0();
    if (s2) { asm volatile("s_waitcnt vmcnt(4)" ::: "memory"); }
    else    { asm volatile("s_waitcnt vmcnt(0)" ::: "memory"); }
    PHASE_SYNC_IN();
  }

  // epilogue: C/D layout col=lane&15, row=(lane>>4)*4+jj
  const int orow = bm * 256 + wr * 128 + ((lane >> 4) << 2);
  const int ocol = bn * 256 + wc * 64 + (lane & 15);
#pragma unroll
  for (int mf = 0; mf < 8; ++mf)
#pragma unroll
    for (int nf = 0; nf < 4; ++nf)
#pragma unroll
      for (int jj = 0; jj < 4; ++jj)
        out[(size_t)(orow + mf * 16 + jj) * N_DIM + ocol + nf * 16] =
            acc[mf][nf][jj];
}

// ---------------------------------------------------------------- launch
extern "C" void kernel_launch(void* const* d_in, const int* in_sizes, int n_in,
                              void* d_out, int out_size, void* d_ws, size_t ws_size,
                              hipStream_t stream) {
  const float* x = (const float*)d_in[0];
  const float* scales = (const float*)d_in[1];
  const float* lora_a = (const float*)d_in[2];
  const float* lora_b = (const float*)d_in[3];
  const int* qweight = (const int*)d_in[4];
  const int* qzeros = (const int*)d_in[5];
  float* out = (float*)d_out;

  unsigned short* Xe = (unsigned short*)d_ws;
  unsigned short* Wt = Xe + (size_t)M_DIM * KP;

  cvt_x_kernel<<<2048, 256, 0, stream>>>(x, Xe);
  lora_t_kernel<<<M_DIM / 16, 256, 0, stream>>>(x, lora_a, Xe);
  dequant_kernel<<<dim3(N_DIM / 64, K_DIM / 64), 256, 0, stream>>>(qweight, qzeros,
                                                                   scales, Wt);
  lorab_t_kernel<<<N_DIM / 64, 256, 0, stream>>>(lora_b, Wt);
  gemm_kernel<<<dim3((N_DIM / 256) * (M_DIM / 256)), 512, 0, stream>>>(Xe, Wt, out);
}